// Round 4
// baseline (331.508 us; speedup 1.0000x reference)
//
#include <hip/hip_runtime.h>
#include <math.h>

// spe_self_atten: out[b] = softmax( (Xb Xb^T) / max(n_i n_j, eps) ) Xb + Xb
// B=256, C=200, L=1024. f32 in/out, bf16 MFMA internally. Residual via P += I.
// Round 4: two-kernel split. Kernel A: Gram + softmax -> P (bf16, +I, padded)
// in d_ws; grid 2B row-split, 2 blocks/CU (61 KB LDS), twin blocks on same XCD
// for L2 slab sharing. Kernel B: out = P @ X; P fragments read from global,
// X chunks staged in LDS (34 KB), 2 blocks/CU, conflict-free XOR staging.

typedef unsigned int uint32;
typedef __attribute__((ext_vector_type(8))) short bf16x8;   // 8 bf16 (4 VGPRs)
typedef __attribute__((ext_vector_type(4))) float f32x4;    // MFMA accum

#define CC 200
#define LL 1024
#define EPSV 1e-8f
#define XASTR 36    // slab row stride (dw), == 4 mod 32
#define PWS 112     // P row stride in ws (dw) = 224 bf16
#define XBSTR 132   // kernel-B chunk col stride (dw)

__device__ __forceinline__ uint32 bfb(float f) {
  // f32 -> bf16 bits, round-to-nearest-even
  uint32 u = __float_as_uint(f);
  u += 0x7fffu + ((u >> 16) & 1u);
  return u >> 16;
}

// ===========================================================================
// Kernel A: Gram rows (half per block) + softmax -> P bf16 in ws
// ===========================================================================
__global__ __launch_bounds__(512, 4)
void gram_sm_kernel(const float* __restrict__ x, uint32* __restrict__ pws) {
  const int tid  = threadIdx.x;
  const int lane = tid & 63;
  const int w    = tid >> 6;
  const int lm   = lane & 15;
  const int lg   = lane >> 4;
  const int nb   = gridDim.x >> 1;
  const int bid  = blockIdx.x;
  const int half = (bid >= nb) ? 1 : 0;
  const int batch = bid - half * nb;          // twins (b, b+nb): same XCD (nb%8==0)
  const float* xb = x + (size_t)batch * (CC * LL);
  uint32* pgl     = pws + (size_t)batch * (208 * PWS);

  const int hb     = half ? 7 : 0;            // first owned row-tile
  const int ntiles = half ? 6 : 7;
  const int dbase  = half ? 0 : 7;            // diag tiles for norms of other half
  const int ndiag  = 13 - ntiles;

  // LDS: xa0 [0,7488) + xa1 [7488,14976) slab double-buffer (208 x 72 bf16,
  // 36 dw stride) + norms [14976,15184) = 60,736 B -> 2 blocks/CU.
  __shared__ uint32 LDS[15184];
  uint32* xa0   = LDS;
  uint32* xa1   = LDS + 7488;
  float*  norms = (float*)(LDS + 14976);

  const f32x4 fz = {0.f, 0.f, 0.f, 0.f};
  f32x4 acc[13];
  #pragma unroll
  for (int j = 0; j < 13; ++j) acc[j] = fz;

  // zero pad rows 200..207 of both slab buffers
  if (tid < 288) { xa0[7200 + tid] = 0u; xa1[7200 + tid] = 0u; }

  float4 vst[7];
  #pragma unroll
  for (int i = 0; i < 7; ++i) {       // stage slab 0 (k=0..63)
    int idx = tid + i * 512;
    if (idx < 3200) {
      int row = idx >> 4, c4 = idx & 15;
      vst[i] = *(const float4*)(xb + row * LL + c4 * 4);
    }
  }
  #pragma unroll
  for (int i = 0; i < 7; ++i) {
    int idx = tid + i * 512;
    if (idx < 3200) {
      int row = idx >> 4, c4 = idx & 15;
      uint2 wv;
      wv.x = bfb(vst[i].x) | (bfb(vst[i].y) << 16);
      wv.y = bfb(vst[i].z) | (bfb(vst[i].w) << 16);
      *(uint2*)&xa0[row * XASTR + c4 * 2] = wv;
    }
  }

  for (int s = 0; s < 16; ++s) {
    __syncthreads();                   // slab s visible
    if (s + 1 < 16) {                  // issue next-slab loads early
      #pragma unroll
      for (int i = 0; i < 7; ++i) {
        int idx = tid + i * 512;
        if (idx < 3200) {
          int row = idx >> 4, c4 = idx & 15;
          vst[i] = *(const float4*)(xb + row * LL + (s + 1) * 64 + c4 * 4);
        }
      }
    }
    const uint32* cur = (s & 1) ? xa1 : xa0;
    #pragma unroll
    for (int ks = 0; ks < 2; ++ks) {
      if (w < ntiles) {
        bf16x8 a = *(const bf16x8*)&cur[((hb + w) * 16 + lm) * XASTR + ks * 16 + lg * 4];
        #pragma unroll
        for (int ct = 0; ct < 13; ++ct) {
          bf16x8 b = *(const bf16x8*)&cur[(ct * 16 + lm) * XASTR + ks * 16 + lg * 4];
          acc[ct] = __builtin_amdgcn_mfma_f32_16x16x32_bf16(a, b, acc[ct], 0, 0, 0);
        }
      } else if (w == ntiles) {        // spare wave: other half's diag tiles
        #pragma unroll
        for (int d = 0; d < 7; ++d) {
          if (d < ndiag) {
            bf16x8 f = *(const bf16x8*)&cur[((dbase + d) * 16 + lm) * XASTR + ks * 16 + lg * 4];
            acc[d] = __builtin_amdgcn_mfma_f32_16x16x32_bf16(f, f, acc[d], 0, 0, 0);
          }
        }
      }
    }
    if (s + 1 < 16) {                  // write staged regs -> other buffer
      uint32* nxt = (s & 1) ? xa0 : xa1;
      #pragma unroll
      for (int i = 0; i < 7; ++i) {
        int idx = tid + i * 512;
        if (idx < 3200) {
          int row = idx >> 4, c4 = idx & 15;
          uint2 wv;
          wv.x = bfb(vst[i].x) | (bfb(vst[i].y) << 16);
          wv.y = bfb(vst[i].z) | (bfb(vst[i].w) << 16);
          *(uint2*)&nxt[row * XASTR + c4 * 2] = wv;
        }
      }
    }
  }

  // norms (all 208 rows) from Gram diagonals
  if (w < ntiles) {
    const int t = hb + w;
    #pragma unroll
    for (int ct = 0; ct < 13; ++ct) {
      if (ct == t) {
        #pragma unroll
        for (int r = 0; r < 4; ++r) {
          int ri = lg * 4 + r;
          if (lm == ri) norms[t * 16 + ri] = sqrtf(acc[ct][r]);
        }
      }
    }
  } else if (w == ntiles) {
    #pragma unroll
    for (int d = 0; d < 7; ++d) {
      if (d < ndiag) {
        int t = dbase + d;
        #pragma unroll
        for (int r = 0; r < 4; ++r) {
          int ri = lg * 4 + r;
          if (lm == ri) norms[t * 16 + ri] = sqrtf(acc[d][r]);
        }
      }
    }
  }
  __syncthreads();

  // softmax own rows + (P+I) -> global ws (bf16 pairs)
  if (w < ntiles) {
    const int t = hb + w;
    float cn[13];
    #pragma unroll
    for (int ct = 0; ct < 13; ++ct) cn[ct] = norms[ct * 16 + lm];

    #pragma unroll
    for (int r = 0; r < 4; ++r) {
      int grow = t * 16 + lg * 4 + r;
      float rn = norms[grow];
      float sv[13];
      float m = -INFINITY;
      #pragma unroll
      for (int ct = 0; ct < 13; ++ct) {
        int gc = ct * 16 + lm;
        float sval = acc[ct][r] / fmaxf(rn * cn[ct], EPSV);
        sval = (gc < CC) ? sval : -INFINITY;
        sv[ct] = sval;
        m = fmaxf(m, sval);
      }
      #pragma unroll
      for (int off = 1; off < 16; off <<= 1) m = fmaxf(m, __shfl_xor(m, off));
      float sum = 0.f;
      #pragma unroll
      for (int ct = 0; ct < 13; ++ct) {
        float e = __expf(sv[ct] - m);
        sv[ct] = e;
        sum += e;
      }
      #pragma unroll
      for (int off = 1; off < 16; off <<= 1) sum += __shfl_xor(sum, off);
      float inv = 1.0f / sum;
      #pragma unroll
      for (int ct = 0; ct < 13; ++ct) {
        int gc = ct * 16 + lm;
        float p = sv[ct] * inv + ((gc == grow) ? 1.0f : 0.0f);   // P += I
        uint32 pb16 = bfb(p);
        uint32 qb = (uint32)__shfl_xor((int)pb16, 1);
        if (!(lane & 1)) pgl[grow * PWS + ct * 8 + (lm >> 1)] = pb16 | (qb << 16);
      }
    }
    // zero P cols 200..223 (dw 100..111) for owned tile (after softmax writes)
    #pragma unroll
    for (int i = 0; i < 3; ++i) {
      int idx = lane + i * 64;         // 192 = 16 rows x 12 dw
      int rr = idx & 15, c = idx >> 4;
      pgl[(t * 16 + rr) * PWS + 100 + c] = 0u;
    }
  }
}

// ===========================================================================
// Kernel B: out = (P+I) @ Xb ; P fragments from global ws, X chunks via LDS
// ===========================================================================
__global__ __launch_bounds__(512, 4)
void pv_kernel(const float* __restrict__ x, const uint32* __restrict__ pws,
               float* __restrict__ out) {
  const int tid  = threadIdx.x;
  const int lane = tid & 63;
  const int w    = tid >> 6;
  const int lm   = lane & 15;
  const int lg   = lane >> 4;
  const int nb   = gridDim.x >> 1;
  const int bid  = blockIdx.x;
  const int half = (bid >= nb) ? 1 : 0;
  const int batch = bid - half * nb;
  const float* xb = x + (size_t)batch * (CC * LL);
  float* ob       = out + (size_t)batch * (CC * LL);
  const uint32* pgl = pws + (size_t)batch * (208 * PWS);

  const bool two = (w < 5);            // waves 0..4 own row-tiles {w, w+8}
  const int rb0 = w;
  const int rb1 = two ? (w + 8) : w;

  // LDS: chunk buffer, col-major kpair-packed, 64 cols x 132 dw = 33,792 B
  __shared__ uint32 xbuf[8448];

  // A-fragments from global P (L2/L3-resident)
  bf16x8 pa[2][7];
  #pragma unroll
  for (int ks = 0; ks < 7; ++ks) {
    pa[0][ks] = *(const bf16x8*)&pgl[(rb0 * 16 + lm) * PWS + ks * 16 + lg * 4];
    if (two)
      pa[1][ks] = *(const bf16x8*)&pgl[(rb1 * 16 + lm) * PWS + ks * 16 + lg * 4];
  }

  const f32x4 fz = {0.f, 0.f, 0.f, 0.f};
  for (int nc = 0; nc < 8; ++nc) {
    const int n0 = half * 512 + nc * 64;
    __syncthreads();                   // xbuf free
    // stage: thread covers col=lane, 14 kpairs (kp = p*8+w), XOR-swizzled so
    // lanes == mod 8 (same bank) write different 4-dw groups.
    #pragma unroll
    for (int p = 0; p < 14; ++p) {
      int kp = p * 8 + w;
      int r0 = kp * 2, r1 = r0 + 1;
      float va = (r0 < CC) ? xb[r0 * LL + n0 + lane] : 0.f;
      float vb = (r1 < CC) ? xb[r1 * LL + n0 + lane] : 0.f;
      int sk = kp ^ (((lane >> 3) & 7) << 2);
      xbuf[lane * XBSTR + sk] = bfb(va) | (bfb(vb) << 16);
    }
    __syncthreads();                   // xbuf ready

    f32x4 acc2[2][4];
    #pragma unroll
    for (int i = 0; i < 2; ++i)
      #pragma unroll
      for (int j = 0; j < 4; ++j) acc2[i][j] = fz;

    #pragma unroll
    for (int ks = 0; ks < 7; ++ks) {   // K = 224 (P cols 200..223 zero)
      #pragma unroll
      for (int ct = 0; ct < 4; ++ct) {
        int col = ct * 16 + lm;
        int kpb = ks * 16 + lg * 4;
        int skb = kpb ^ (((col >> 3) & 7) << 2);   // writer lane == col
        bf16x8 b = *(const bf16x8*)&xbuf[col * XBSTR + skb];
        acc2[0][ct] = __builtin_amdgcn_mfma_f32_16x16x32_bf16(pa[0][ks], b, acc2[0][ct], 0, 0, 0);
        if (two)
          acc2[1][ct] = __builtin_amdgcn_mfma_f32_16x16x32_bf16(pa[1][ks], b, acc2[1][ct], 0, 0, 0);
      }
    }

    #pragma unroll
    for (int rbi = 0; rbi < 2; ++rbi) {
      if (rbi == 0 || two) {
        int rb = rbi ? rb1 : rb0;
        #pragma unroll
        for (int ct = 0; ct < 4; ++ct) {
          #pragma unroll
          for (int r = 0; r < 4; ++r) {
            int grow = rb * 16 + lg * 4 + r;
            if (grow < CC) ob[grow * LL + n0 + ct * 16 + lm] = acc2[rbi][ct][r];
          }
        }
      }
    }
  }
}

// ===========================================================================
// Fallback: round-3 fused kernel (used only if ws_size is too small)
// ===========================================================================
#define PLSTR 116
__global__ __launch_bounds__(512, 1)
void spe_attn_fused(const float* __restrict__ x, float* __restrict__ out) {
  const int tid  = threadIdx.x;
  const int lane = tid & 63;
  const int w    = tid >> 6;
  const int lm   = lane & 15;
  const int lg   = lane >> 4;
  const int bidx = blockIdx.x;
  const float* xb = x + (size_t)bidx * (CC * LL);
  float* ob       = out + (size_t)bidx * (CC * LL);

  __shared__ uint32 LDS[39312];
  uint32* pl    = LDS;
  uint32* xa0   = LDS + 24128;
  uint32* xa1   = LDS + 31616;
  uint32* xbufl = LDS + 24128;
  float*  norms = (float*)(LDS + 39104);

  const bool two = (w < 5);
  const int rb0 = w;
  const int rb1 = two ? (w + 8) : w;

  const f32x4 fz = {0.f, 0.f, 0.f, 0.f};
  f32x4 acc[2][13];
  #pragma unroll
  for (int i = 0; i < 2; ++i)
    #pragma unroll
    for (int j = 0; j < 13; ++j) acc[i][j] = fz;

  if (tid < 288) { xa0[7200 + tid] = 0u; xa1[7200 + tid] = 0u; }

  float4 vst[7];
  #pragma unroll
  for (int i = 0; i < 7; ++i) {
    int idx = tid + i * 512;
    if (idx < 3200) {
      int row = idx >> 4, c4 = idx & 15;
      vst[i] = *(const float4*)(xb + row * LL + c4 * 4);
    }
  }
  #pragma unroll
  for (int i = 0; i < 7; ++i) {
    int idx = tid + i * 512;
    if (idx < 3200) {
      int row = idx >> 4, c4 = idx & 15;
      uint2 wv;
      wv.x = bfb(vst[i].x) | (bfb(vst[i].y) << 16);
      wv.y = bfb(vst[i].z) | (bfb(vst[i].w) << 16);
      *(uint2*)&xa0[row * XASTR + c4 * 2] = wv;
    }
  }

  for (int s = 0; s < 16; ++s) {
    __syncthreads();
    if (s + 1 < 16) {
      #pragma unroll
      for (int i = 0; i < 7; ++i) {
        int idx = tid + i * 512;
        if (idx < 3200) {
          int row = idx >> 4, c4 = idx & 15;
          vst[i] = *(const float4*)(xb + row * LL + (s + 1) * 64 + c4 * 4);
        }
      }
    }
    const uint32* cur = (s & 1) ? xa1 : xa0;
    #pragma unroll
    for (int ks = 0; ks < 2; ++ks) {
      bf16x8 a0 = *(const bf16x8*)&cur[(rb0 * 16 + lm) * XASTR + ks * 16 + lg * 4];
      bf16x8 a1 = a0;
      if (two) a1 = *(const bf16x8*)&cur[(rb1 * 16 + lm) * XASTR + ks * 16 + lg * 4];
      #pragma unroll
      for (int ct = 0; ct < 13; ++ct) {
        bf16x8 bf = *(const bf16x8*)&cur[(ct * 16 + lm) * XASTR + ks * 16 + lg * 4];
        acc[0][ct] = __builtin_amdgcn_mfma_f32_16x16x32_bf16(a0, bf, acc[0][ct], 0, 0, 0);
        if (two)
          acc[1][ct] = __builtin_amdgcn_mfma_f32_16x16x32_bf16(a1, bf, acc[1][ct], 0, 0, 0);
      }
    }
    if (s + 1 < 16) {
      uint32* nxt = (s & 1) ? xa0 : xa1;
      #pragma unroll
      for (int i = 0; i < 7; ++i) {
        int idx = tid + i * 512;
        if (idx < 3200) {
          int row = idx >> 4, c4 = idx & 15;
          uint2 wv;
          wv.x = bfb(vst[i].x) | (bfb(vst[i].y) << 16);
          wv.y = bfb(vst[i].z) | (bfb(vst[i].w) << 16);
          *(uint2*)&nxt[row * XASTR + c4 * 2] = wv;
        }
      }
    }
  }

  #pragma unroll
  for (int rbi = 0; rbi < 2; ++rbi) {
    if (rbi == 0 || two) {
      int rb = rbi ? rb1 : rb0;
      #pragma unroll
      for (int ct = 0; ct < 13; ++ct) {
        if (ct == rb) {
          #pragma unroll
          for (int r = 0; r < 4; ++r) {
            int ri = lg * 4 + r;
            if (lm == ri) norms[rb * 16 + ri] = sqrtf(acc[rbi][ct][r]);
          }
        }
      }
    }
  }
  __syncthreads();

  float cn[13];
  #pragma unroll
  for (int ct = 0; ct < 13; ++ct) cn[ct] = norms[ct * 16 + lm];

  #pragma unroll
  for (int rbi = 0; rbi < 2; ++rbi) {
    if (rbi == 0 || two) {
      int rb = rbi ? rb1 : rb0;
      #pragma unroll
      for (int r = 0; r < 4; ++r) {
        int grow = rb * 16 + lg * 4 + r;
        float rn = norms[grow];
        float sv[13];
        float m = -INFINITY;
        #pragma unroll
        for (int ct = 0; ct < 13; ++ct) {
          int gc = ct * 16 + lm;
          float sval = acc[rbi][ct][r] / fmaxf(rn * cn[ct], EPSV);
          sval = (gc < CC) ? sval : -INFINITY;
          sv[ct] = sval;
          m = fmaxf(m, sval);
        }
        #pragma unroll
        for (int off = 1; off < 16; off <<= 1) m = fmaxf(m, __shfl_xor(m, off));
        float sum = 0.f;
        #pragma unroll
        for (int ct = 0; ct < 13; ++ct) {
          float e = __expf(sv[ct] - m);
          sv[ct] = e;
          sum += e;
        }
        #pragma unroll
        for (int off = 1; off < 16; off <<= 1) sum += __shfl_xor(sum, off);
        float inv = 1.0f / sum;
        #pragma unroll
        for (int ct = 0; ct < 13; ++ct) {
          int gc = ct * 16 + lm;
          float p = sv[ct] * inv + ((gc == grow) ? 1.0f : 0.0f);
          uint32 pb = bfb(p);
          uint32 qb = (uint32)__shfl_xor((int)pb, 1);
          if (!(lane & 1)) pl[grow * PLSTR + ct * 8 + (lm >> 1)] = pb | (qb << 16);
        }
      }
      for (int i = lane; i < 256; i += 64) {
        int rr = i >> 4, c = i & 15;
        if (c < 12) pl[(rb * 16 + rr) * PLSTR + 100 + c] = 0u;
      }
    }
  }

  bf16x8 pa[2][7];
  #pragma unroll
  for (int ks = 0; ks < 7; ++ks) {
    pa[0][ks] = *(const bf16x8*)&pl[(rb0 * 16 + lm) * PLSTR + ks * 16 + lg * 4];
    if (two)
      pa[1][ks] = *(const bf16x8*)&pl[(rb1 * 16 + lm) * PLSTR + ks * 16 + lg * 4];
  }

  float pva[14], pvb[14];
  #pragma unroll
  for (int p = 0; p < 14; ++p) {
    int kp = p * 8 + w;
    int r0 = kp * 2, r1 = r0 + 1;
    pva[p] = (r0 < CC) ? xb[r0 * LL + lane] : 0.f;
    pvb[p] = (r1 < CC) ? xb[r1 * LL + lane] : 0.f;
  }

  for (int nc = 0; nc < 16; ++nc) {
    const int n0 = nc * 64;
    __syncthreads();
    #pragma unroll
    for (int p = 0; p < 14; ++p) {
      int kp = p * 8 + w;
      xbufl[lane * XBSTR + kp] = bfb(pva[p]) | (bfb(pvb[p]) << 16);
    }
    __syncthreads();
    if (nc + 1 < 16) {
      const int n1 = (nc + 1) * 64;
      #pragma unroll
      for (int p = 0; p < 14; ++p) {
        int kp = p * 8 + w;
        int r0 = kp * 2, r1 = r0 + 1;
        pva[p] = (r0 < CC) ? xb[r0 * LL + n1 + lane] : 0.f;
        pvb[p] = (r1 < CC) ? xb[r1 * LL + n1 + lane] : 0.f;
      }
    }

    f32x4 acc2[2][4];
    #pragma unroll
    for (int i = 0; i < 2; ++i)
      #pragma unroll
      for (int j = 0; j < 4; ++j) acc2[i][j] = fz;

    #pragma unroll
    for (int ks = 0; ks < 7; ++ks) {
      #pragma unroll
      for (int ct = 0; ct < 4; ++ct) {
        bf16x8 b = *(const bf16x8*)&xbufl[(ct * 16 + lm) * XBSTR + ks * 16 + lg * 4];
        acc2[0][ct] = __builtin_amdgcn_mfma_f32_16x16x32_bf16(pa[0][ks], b, acc2[0][ct], 0, 0, 0);
        if (two)
          acc2[1][ct] = __builtin_amdgcn_mfma_f32_16x16x32_bf16(pa[1][ks], b, acc2[1][ct], 0, 0, 0);
      }
    }

    #pragma unroll
    for (int rbi = 0; rbi < 2; ++rbi) {
      if (rbi == 0 || two) {
        int rb = rbi ? rb1 : rb0;
        #pragma unroll
        for (int ct = 0; ct < 4; ++ct) {
          #pragma unroll
          for (int r = 0; r < 4; ++r) {
            int grow = rb * 16 + lg * 4 + r;
            if (grow < CC) ob[grow * LL + n0 + ct * 16 + lm] = acc2[rbi][ct][r];
          }
        }
      }
    }
  }
}

extern "C" void kernel_launch(void* const* d_in, const int* in_sizes, int n_in,
                              void* d_out, int out_size, void* d_ws, size_t ws_size,
                              hipStream_t stream) {
  const float* x = (const float*)d_in[0];
  float* out = (float*)d_out;
  const int B = in_sizes[0] / (CC * LL);          // 256
  const size_t need = (size_t)B * 208 * PWS * 4;  // ~27 MB for P
  if (ws_size >= need) {
    gram_sm_kernel<<<dim3(2 * B), dim3(512), 0, stream>>>(x, (uint32*)d_ws);
    pv_kernel<<<dim3(2 * B), dim3(512), 0, stream>>>(x, (const uint32*)d_ws, out);
  } else {
    spe_attn_fused<<<dim3(B), dim3(512), 0, stream>>>(x, out);
  }
}

// Round 5
// 295.619 us; speedup vs baseline: 1.1214x; 1.1214x over previous
//
#include <hip/hip_runtime.h>
#include <math.h>

// spe_self_atten: out[b] = softmax( (Xb Xb^T) / max(n_i n_j, eps) ) Xb + Xb
// B=256, C=200, L=1024. f32 in/out, bf16 MFMA internally. Residual via P += I.
// Round 5: fused row-split. Grid 2B; twins (b, b+B) share an XCD (L2 slab
// sharing, verified by round-4-A). 61 KB LDS -> 2 blocks/CU so independent
// barrier domains overlap. P lives only in registers + per-wave transient LDS
// slots (no global round-trip). Phase 2 in-block: ping-pong 64-col chunks,
// one barrier per chunk, b64 staging writes, b128 fragment reads, prefetch.

typedef unsigned int uint32;
typedef __attribute__((ext_vector_type(8))) short bf16x8;   // 8 bf16 (4 VGPRs)
typedef __attribute__((ext_vector_type(4))) float f32x4;    // MFMA accum

#define CC 200
#define LL 1024
#define EPSV 1e-8f
#define XASTR 36    // phase-1 slab row stride (dw), == 4 mod 32
#define TSTR 116    // P-tile / chunk col stride (dw), == 20 mod 32, mult of 4

__device__ __forceinline__ uint32 bfb(float f) {
  // f32 -> bf16 bits, round-to-nearest-even
  uint32 u = __float_as_uint(f);
  u += 0x7fffu + ((u >> 16) & 1u);
  return u >> 16;
}

__global__ __launch_bounds__(512, 4)
void spe_attn_kernel(const float* __restrict__ x, float* __restrict__ out) {
  const int tid  = threadIdx.x;
  const int lane = tid & 63;
  const int w    = tid >> 6;       // wave 0..7
  const int lm   = lane & 15;
  const int lg   = lane >> 4;
  const int nb   = gridDim.x >> 1;
  const int bid  = blockIdx.x;
  const int half = (bid >= nb) ? 1 : 0;
  const int batch = bid - half * nb;          // twins (b, b+nb): same XCD (nb%8==0)
  const float* xb = x + (size_t)batch * (CC * LL);
  float* ob       = out + (size_t)batch * (CC * LL);

  const int hb     = half ? 7 : 0;            // first owned row-tile
  const int ntiles = half ? 6 : 7;            // row tiles owned by this block
  const int dbase  = half ? 0 : 7;            // diag tiles for other half's norms
  const int ndiag  = 13 - ntiles;

  // LDS (dwords), 15184 dw = 60,736 B -> 2 blocks/CU:
  //  phase 1: xa0 [0,7488) + xa1 [7488,14976) slab dbuf (208 x 72 bf16, 36 dw)
  //  norms   [14976,15184): 208 floats
  //  phase 2 (aliases [0,14976)):
  //    trp slot per wave w: [w*1856, +1856): 16 rows x 232 bf16 (116 dw) transient
  //    xb0 [0,7424), xb1 [7488,14912): ping-pong chunk, col-major 64 x 116 dw
  __shared__ uint32 LDS[15184];
  uint32* xa0   = LDS;
  uint32* xa1   = LDS + 7488;
  float*  norms = (float*)(LDS + 14976);
  uint32* trp   = LDS + w * 1856;
  uint32* xbf0  = LDS;
  uint32* xbf1  = LDS + 7488;

  // ---------------- Phase 1: Gram rows for this half (round-4-A verified) ----
  const f32x4 fz = {0.f, 0.f, 0.f, 0.f};
  f32x4 acc[13];
  #pragma unroll
  for (int j = 0; j < 13; ++j) acc[j] = fz;

  // zero pad rows 200..207 of both slab buffers
  if (tid < 288) { xa0[7200 + tid] = 0u; xa1[7200 + tid] = 0u; }

  float4 vst[7];
  #pragma unroll
  for (int i = 0; i < 7; ++i) {       // stage slab 0 (k=0..63)
    int idx = tid + i * 512;
    if (idx < 3200) {
      int row = idx >> 4, c4 = idx & 15;
      vst[i] = *(const float4*)(xb + row * LL + c4 * 4);
    }
  }
  #pragma unroll
  for (int i = 0; i < 7; ++i) {
    int idx = tid + i * 512;
    if (idx < 3200) {
      int row = idx >> 4, c4 = idx & 15;
      uint2 wv;
      wv.x = bfb(vst[i].x) | (bfb(vst[i].y) << 16);
      wv.y = bfb(vst[i].z) | (bfb(vst[i].w) << 16);
      *(uint2*)&xa0[row * XASTR + c4 * 2] = wv;
    }
  }

  for (int s = 0; s < 16; ++s) {
    __syncthreads();                   // slab s visible
    if (s + 1 < 16) {                  // issue next-slab loads early
      #pragma unroll
      for (int i = 0; i < 7; ++i) {
        int idx = tid + i * 512;
        if (idx < 3200) {
          int row = idx >> 4, c4 = idx & 15;
          vst[i] = *(const float4*)(xb + row * LL + (s + 1) * 64 + c4 * 4);
        }
      }
    }
    const uint32* cur = (s & 1) ? xa1 : xa0;
    __builtin_amdgcn_s_setprio(1);
    #pragma unroll
    for (int ks = 0; ks < 2; ++ks) {
      if (w < ntiles) {
        bf16x8 a = *(const bf16x8*)&cur[((hb + w) * 16 + lm) * XASTR + ks * 16 + lg * 4];
        #pragma unroll
        for (int ct = 0; ct < 13; ++ct) {
          bf16x8 b = *(const bf16x8*)&cur[(ct * 16 + lm) * XASTR + ks * 16 + lg * 4];
          acc[ct] = __builtin_amdgcn_mfma_f32_16x16x32_bf16(a, b, acc[ct], 0, 0, 0);
        }
      } else if (w == ntiles) {        // spare wave: other half's diag tiles
        #pragma unroll
        for (int d = 0; d < 7; ++d) {
          if (d < ndiag) {
            bf16x8 f = *(const bf16x8*)&cur[((dbase + d) * 16 + lm) * XASTR + ks * 16 + lg * 4];
            acc[d] = __builtin_amdgcn_mfma_f32_16x16x32_bf16(f, f, acc[d], 0, 0, 0);
          }
        }
      }
    }
    __builtin_amdgcn_s_setprio(0);
    if (s + 1 < 16) {                  // write staged regs -> other buffer
      uint32* nxt = (s & 1) ? xa0 : xa1;
      #pragma unroll
      for (int i = 0; i < 7; ++i) {
        int idx = tid + i * 512;
        if (idx < 3200) {
          int row = idx >> 4, c4 = idx & 15;
          uint2 wv;
          wv.x = bfb(vst[i].x) | (bfb(vst[i].y) << 16);
          wv.y = bfb(vst[i].z) | (bfb(vst[i].w) << 16);
          *(uint2*)&nxt[row * XASTR + c4 * 2] = wv;
        }
      }
    }
  }

  // ---------------- norms (all 208 rows) from Gram diagonals -----------------
  if (w < ntiles) {
    const int t = hb + w;
    #pragma unroll
    for (int ct = 0; ct < 13; ++ct) {
      if (ct == t) {
        #pragma unroll
        for (int r = 0; r < 4; ++r) {
          int ri = lg * 4 + r;
          if (lm == ri) norms[t * 16 + ri] = sqrtf(acc[ct][r]);
        }
      }
    }
  } else if (w == ntiles) {
    #pragma unroll
    for (int d = 0; d < 7; ++d) {
      if (d < ndiag) {
        int t = dbase + d;
        #pragma unroll
        for (int r = 0; r < 4; ++r) {
          int ri = lg * 4 + r;
          if (lm == ri) norms[t * 16 + ri] = sqrtf(acc[d][r]);
        }
      }
    }
  }
  __syncthreads();   // norms visible; also: last slab reads done before trp writes

  // ---------------- softmax own rows + (P+I) -> per-wave trp slot ------------
  bf16x8 pa[7];                        // phase-2 A fragments (this wave's tile)
  if (w < ntiles) {
    const int t = hb + w;
    float cn[13];
    #pragma unroll
    for (int ct = 0; ct < 13; ++ct) cn[ct] = norms[ct * 16 + lm];

    #pragma unroll
    for (int r = 0; r < 4; ++r) {
      int grow = t * 16 + lg * 4 + r;
      int lrow = lg * 4 + r;
      float rn = norms[grow];
      float sv[13];
      float m = -INFINITY;
      #pragma unroll
      for (int ct = 0; ct < 13; ++ct) {
        int gc = ct * 16 + lm;
        float sval = acc[ct][r] / fmaxf(rn * cn[ct], EPSV);
        sval = (gc < CC) ? sval : -INFINITY;
        sv[ct] = sval;
        m = fmaxf(m, sval);
      }
      #pragma unroll
      for (int off = 1; off < 16; off <<= 1) m = fmaxf(m, __shfl_xor(m, off));
      float sum = 0.f;
      #pragma unroll
      for (int ct = 0; ct < 13; ++ct) {
        float e = __expf(sv[ct] - m);
        sv[ct] = e;
        sum += e;
      }
      #pragma unroll
      for (int off = 1; off < 16; off <<= 1) sum += __shfl_xor(sum, off);
      float inv = 1.0f / sum;
      #pragma unroll
      for (int ct = 0; ct < 13; ++ct) {
        int gc = ct * 16 + lm;
        float p = sv[ct] * inv + ((gc == grow) ? 1.0f : 0.0f);   // P += I
        uint32 pb = bfb(p);
        uint32 qb = (uint32)__shfl_xor((int)pb, 1);
        if (!(lane & 1)) trp[lrow * TSTR + ct * 8 + (lm >> 1)] = pb | (qb << 16);
      }
    }
    // zero K-pad cols 208..231 (dw 104..111); cols 200..207 already 0 (exp(-inf))
    #pragma unroll
    for (int i = 0; i < 2; ++i) {
      int idx = lane + i * 64;         // 128 = 16 rows x 8 dw
      int rr = idx >> 3, c = idx & 7;
      trp[rr * TSTR + 104 + c] = 0u;
    }
    // A-fragments: read own slot transposed (intra-wave, no barrier)
    #pragma unroll
    for (int ks = 0; ks < 7; ++ks)
      pa[ks] = *(const bf16x8*)&trp[lm * TSTR + ks * 16 + lg * 4];
  }
  __syncthreads();                     // all pa built before slots become xbufs

  // ---------------- Phase 2: out rows = (P+I) @ Xb, 16 chunks of 64 cols -----
  // Staging: thread (w, lane) covers col=lane, kpp = p*8+w (kpp 0..55), rows
  // 4*kpp..+3 packed as 2 kpair dwords, one b64 write. Prefetched 1 chunk ahead.
  float pv[7][4];
  #pragma unroll
  for (int p = 0; p < 7; ++p) {        // preload chunk 0
    int rb4 = (p * 8 + w) * 4;
    #pragma unroll
    for (int q = 0; q < 4; ++q) {
      int r = rb4 + q;
      pv[p][q] = (r < CC) ? xb[r * LL + lane] : 0.f;
    }
  }
  #pragma unroll
  for (int p = 0; p < 7; ++p) {        // write chunk 0 -> xbf0
    int kpp = p * 8 + w;
    uint2 wv;
    wv.x = bfb(pv[p][0]) | (bfb(pv[p][1]) << 16);
    wv.y = bfb(pv[p][2]) | (bfb(pv[p][3]) << 16);
    *(uint2*)&xbf0[lane * TSTR + 2 * kpp] = wv;
  }

  for (int nc = 0; nc < 16; ++nc) {
    const int n0 = nc * 64;
    __syncthreads();                   // chunk nc staged by all; nc-2 reads done
    if (nc + 1 < 16) {                 // issue next chunk's loads (hide under MFMA)
      const int n1 = n0 + 64;
      #pragma unroll
      for (int p = 0; p < 7; ++p) {
        int rb4 = (p * 8 + w) * 4;
        #pragma unroll
        for (int q = 0; q < 4; ++q) {
          int r = rb4 + q;
          pv[p][q] = (r < CC) ? xb[r * LL + n1 + lane] : 0.f;
        }
      }
    }

    const uint32* XC = (nc & 1) ? xbf1 : xbf0;
    f32x4 acc2[4] = {fz, fz, fz, fz};
    if (w < ntiles) {
      __builtin_amdgcn_s_setprio(1);
      #pragma unroll
      for (int ks = 0; ks < 7; ++ks) {  // K = 224 (P cols 200..223 zero)
        #pragma unroll
        for (int ct = 0; ct < 4; ++ct) {
          bf16x8 b = *(const bf16x8*)&XC[(ct * 16 + lm) * TSTR + ks * 16 + lg * 4];
          acc2[ct] = __builtin_amdgcn_mfma_f32_16x16x32_bf16(pa[ks], b, acc2[ct], 0, 0, 0);
        }
      }
      __builtin_amdgcn_s_setprio(0);
    }

    if (nc + 1 < 16) {                 // write staged regs -> other buffer
      uint32* XN = (nc & 1) ? xbf0 : xbf1;
      #pragma unroll
      for (int p = 0; p < 7; ++p) {
        int kpp = p * 8 + w;
        uint2 wv;
        wv.x = bfb(pv[p][0]) | (bfb(pv[p][1]) << 16);
        wv.y = bfb(pv[p][2]) | (bfb(pv[p][3]) << 16);
        *(uint2*)&XN[lane * TSTR + 2 * kpp] = wv;
      }
    }

    if (w < ntiles) {                  // store f32 outputs (after ds_writes so
      const int t = hb + w;            // the staging vmcnt doesn't wait on them)
      #pragma unroll
      for (int ct = 0; ct < 4; ++ct) {
        #pragma unroll
        for (int r = 0; r < 4; ++r) {
          int grow = t * 16 + lg * 4 + r;
          if (grow < CC) ob[grow * LL + n0 + ct * 16 + lm] = acc2[ct][r];
        }
      }
    }
  }
}

extern "C" void kernel_launch(void* const* d_in, const int* in_sizes, int n_in,
                              void* d_out, int out_size, void* d_ws, size_t ws_size,
                              hipStream_t stream) {
  const float* x = (const float*)d_in[0];
  float* out = (float*)d_out;
  const int B = in_sizes[0] / (CC * LL);   // 256
  spe_attn_kernel<<<dim3(2 * B), dim3(512), 0, stream>>>(x, out);
}

// Round 7
// 151.045 us; speedup vs baseline: 2.1948x; 1.9572x over previous
//
#include <hip/hip_runtime.h>
#include <math.h>

// spe_self_atten: out[b] = softmax( (Xb Xb^T) / max(n_i n_j, eps) ) Xb + Xb
// B=256, C=200, L=1024. f32 in/out, bf16 MFMA internally. Residual via P += I.
// Round 7: round-3 base (1 block/batch, 512 thr, verified 157us) with phase 2
// swapped to the round-5-verified mechanics: ping-pong chunk buffers with ONE
// barrier per chunk, b64 staging writes (4-way not 8-way conflicts), b128
// unswizzled fragment reads, dual row-tile accumulators, setprio on MFMA.

typedef unsigned int uint32;
typedef __attribute__((ext_vector_type(8))) short bf16x8;   // 8 bf16 (4 VGPRs)
typedef __attribute__((ext_vector_type(4))) float f32x4;    // MFMA accum

#define CC 200
#define LL 1024
#define EPSV 1e-8f
#define PLSTR 116   // P row stride (dw)
#define XASTR 36    // phase-1 slab row stride (dw), == 4 mod 32
#define TSTR 116    // phase-2 chunk col stride (dw), round-5 verified

__device__ __forceinline__ uint32 bfb(float f) {
  // f32 -> bf16 bits, round-to-nearest-even
  uint32 u = __float_as_uint(f);
  u += 0x7fffu + ((u >> 16) & 1u);
  return u >> 16;
}

__global__ __launch_bounds__(512, 1)
void spe_attn_kernel(const float* __restrict__ x, float* __restrict__ out) {
  const int tid  = threadIdx.x;
  const int lane = tid & 63;
  const int w    = tid >> 6;       // wave 0..7
  const int lm   = lane & 15;
  const int lg   = lane >> 4;
  const int bidx = blockIdx.x;
  const float* xb = x + (size_t)bidx * (CC * LL);
  float* ob       = out + (size_t)bidx * (CC * LL);

  // LDS layout (dwords), total 39312 dw = 157,248 B:
  //  pl    [0,24128)      : P bf16, 208 rows x 232 cols (116 dw stride)
  //  xa0   [24128,31616)  : phase-1 slab buf A, 208 rows x 72 bf16 (36 dw)
  //  xa1   [31616,39104)  : phase-1 slab buf B
  //  xbf0/1 (alias xa0/xa1): phase-2 ping-pong chunk, col-major 64 x 116 dw
  //  norms [39104,39312)  : 208 floats
  __shared__ uint32 LDS[39312];
  uint32* pl    = LDS;
  uint32* xa0   = LDS + 24128;
  uint32* xa1   = LDS + 31616;
  uint32* xbf0  = LDS + 24128;
  uint32* xbf1  = LDS + 31616;
  float*  norms = (float*)(LDS + 39104);

  const bool two = (w < 5);            // waves 0..4 own row-tiles {w, w+8}
  const int rb0 = w;
  const int rb1 = two ? (w + 8) : w;

  // ---------------- Phase 1: Gram S = Xb Xb^T (round-3 verbatim) -------------
  const f32x4 fz = {0.f, 0.f, 0.f, 0.f};
  f32x4 acc[2][13];
  #pragma unroll
  for (int i = 0; i < 2; ++i)
    #pragma unroll
    for (int j = 0; j < 13; ++j) acc[i][j] = fz;

  // zero pad rows 200..207 of both slab buffers
  if (tid < 288) { xa0[7200 + tid] = 0u; xa1[7200 + tid] = 0u; }

  float4 vst[7];
  #pragma unroll
  for (int i = 0; i < 7; ++i) {       // stage slab 0 (k=0..63)
    int idx = tid + i * 512;
    if (idx < 3200) {
      int row = idx >> 4, c4 = idx & 15;
      vst[i] = *(const float4*)(xb + row * LL + c4 * 4);
    }
  }
  #pragma unroll
  for (int i = 0; i < 7; ++i) {
    int idx = tid + i * 512;
    if (idx < 3200) {
      int row = idx >> 4, c4 = idx & 15;
      uint2 wv;
      wv.x = bfb(vst[i].x) | (bfb(vst[i].y) << 16);
      wv.y = bfb(vst[i].z) | (bfb(vst[i].w) << 16);
      *(uint2*)&xa0[row * XASTR + c4 * 2] = wv;
    }
  }

  for (int s = 0; s < 16; ++s) {
    __syncthreads();                   // slab s visible
    if (s + 1 < 16) {                  // issue next-slab loads early
      #pragma unroll
      for (int i = 0; i < 7; ++i) {
        int idx = tid + i * 512;
        if (idx < 3200) {
          int row = idx >> 4, c4 = idx & 15;
          vst[i] = *(const float4*)(xb + row * LL + (s + 1) * 64 + c4 * 4);
        }
      }
    }
    const uint32* cur = (s & 1) ? xa1 : xa0;
    __builtin_amdgcn_s_setprio(1);
    #pragma unroll
    for (int ks = 0; ks < 2; ++ks) {
      bf16x8 a0 = *(const bf16x8*)&cur[(rb0 * 16 + lm) * XASTR + ks * 16 + lg * 4];
      bf16x8 a1 = a0;
      if (two) a1 = *(const bf16x8*)&cur[(rb1 * 16 + lm) * XASTR + ks * 16 + lg * 4];
      #pragma unroll
      for (int ct = 0; ct < 13; ++ct) {
        bf16x8 bf = *(const bf16x8*)&cur[(ct * 16 + lm) * XASTR + ks * 16 + lg * 4];
        acc[0][ct] = __builtin_amdgcn_mfma_f32_16x16x32_bf16(a0, bf, acc[0][ct], 0, 0, 0);
        if (two)
          acc[1][ct] = __builtin_amdgcn_mfma_f32_16x16x32_bf16(a1, bf, acc[1][ct], 0, 0, 0);
      }
    }
    __builtin_amdgcn_s_setprio(0);
    if (s + 1 < 16) {                  // write staged regs -> other buffer
      uint32* nxt = (s & 1) ? xa0 : xa1;
      #pragma unroll
      for (int i = 0; i < 7; ++i) {
        int idx = tid + i * 512;
        if (idx < 3200) {
          int row = idx >> 4, c4 = idx & 15;
          uint2 wv;
          wv.x = bfb(vst[i].x) | (bfb(vst[i].y) << 16);
          wv.y = bfb(vst[i].z) | (bfb(vst[i].w) << 16);
          *(uint2*)&nxt[row * XASTR + c4 * 2] = wv;
        }
      }
    }
  }

  // ---------------- norms from Gram diagonal (round-3 verbatim) --------------
  #pragma unroll
  for (int rbi = 0; rbi < 2; ++rbi) {
    if (rbi == 0 || two) {
      int rb = rbi ? rb1 : rb0;
      #pragma unroll
      for (int ct = 0; ct < 13; ++ct) {
        if (ct == rb) {
          #pragma unroll
          for (int r = 0; r < 4; ++r) {
            int ri = lg * 4 + r;
            if (lm == ri) norms[rb * 16 + ri] = sqrtf(acc[rbi][ct][r]);
          }
        }
      }
    }
  }
  __syncthreads();

  // ---------------- softmax rows + (P+I) -> LDS bf16 (round-3 verbatim) ------
  float cn[13];
  #pragma unroll
  for (int ct = 0; ct < 13; ++ct) cn[ct] = norms[ct * 16 + lm];

  #pragma unroll
  for (int rbi = 0; rbi < 2; ++rbi) {
    if (rbi == 0 || two) {
      int rb = rbi ? rb1 : rb0;
      #pragma unroll
      for (int r = 0; r < 4; ++r) {
        int grow = rb * 16 + lg * 4 + r;
        float rn = norms[grow];
        float sv[13];
        float m = -INFINITY;
        #pragma unroll
        for (int ct = 0; ct < 13; ++ct) {
          int gc = ct * 16 + lm;
          float sval = acc[rbi][ct][r] / fmaxf(rn * cn[ct], EPSV);
          sval = (gc < CC) ? sval : -INFINITY;
          sv[ct] = sval;
          m = fmaxf(m, sval);
        }
        #pragma unroll
        for (int off = 1; off < 16; off <<= 1) m = fmaxf(m, __shfl_xor(m, off));
        float sum = 0.f;
        #pragma unroll
        for (int ct = 0; ct < 13; ++ct) {
          float e = __expf(sv[ct] - m);
          sv[ct] = e;
          sum += e;
        }
        #pragma unroll
        for (int off = 1; off < 16; off <<= 1) sum += __shfl_xor(sum, off);
        float inv = 1.0f / sum;
        #pragma unroll
        for (int ct = 0; ct < 13; ++ct) {
          int gc = ct * 16 + lm;
          float p = sv[ct] * inv + ((gc == grow) ? 1.0f : 0.0f);   // P += I
          uint32 pb = bfb(p);
          uint32 qb = (uint32)__shfl_xor((int)pb, 1);
          if (!(lane & 1)) pl[grow * PLSTR + ct * 8 + (lm >> 1)] = pb | (qb << 16);
        }
      }
      // zero P cols 200..223 (dw 100..111) for this row-block
      for (int i = lane; i < 256; i += 64) {
        int rr = i >> 4, c = i & 15;
        if (c < 12) pl[(rb * 16 + rr) * PLSTR + 100 + c] = 0u;
      }
    }
  }

  // A-fragments (own rows only; this wave wrote them -> intra-wave, no barrier)
  bf16x8 pa[2][7];
  #pragma unroll
  for (int ks = 0; ks < 7; ++ks) {
    pa[0][ks] = *(const bf16x8*)&pl[(rb0 * 16 + lm) * PLSTR + ks * 16 + lg * 4];
    if (two)
      pa[1][ks] = *(const bf16x8*)&pl[(rb1 * 16 + lm) * PLSTR + ks * 16 + lg * 4];
  }

  // ---------------- Phase 2: out = (P+I) @ Xb, 16 chunks of 64 cols ----------
  // Round-5-verified mechanics: ping-pong xbf0/xbf1, ONE barrier per chunk.
  // Staging: thread (w,lane) covers col=lane, kpp = p*8+w (kpp 0..55), rows
  // 4*kpp..+3 packed as 2 kpair dwords, one b64 write. Prefetched 1 chunk ahead.
  float pv[7][4];
  #pragma unroll
  for (int p = 0; p < 7; ++p) {        // preload chunk 0
    int rb4 = (p * 8 + w) * 4;
    #pragma unroll
    for (int q = 0; q < 4; ++q) {
      int r = rb4 + q;
      pv[p][q] = (r < CC) ? xb[r * LL + lane] : 0.f;
    }
  }
  #pragma unroll
  for (int p = 0; p < 7; ++p) {        // write chunk 0 -> xbf0 (xa0 is dead:
    int kpp = p * 8 + w;               //  last slab read was xa1, barrier passed)
    uint2 wv;
    wv.x = bfb(pv[p][0]) | (bfb(pv[p][1]) << 16);
    wv.y = bfb(pv[p][2]) | (bfb(pv[p][3]) << 16);
    *(uint2*)&xbf0[lane * TSTR + 2 * kpp] = wv;
  }

  for (int nc = 0; nc < 16; ++nc) {
    const int n0 = nc * 64;
    __syncthreads();                   // chunk nc staged by all; nc-2 reads done
    if (nc + 1 < 16) {                 // issue next chunk's loads (hide under MFMA)
      const int n1 = n0 + 64;
      #pragma unroll
      for (int p = 0; p < 7; ++p) {
        int rb4 = (p * 8 + w) * 4;
        #pragma unroll
        for (int q = 0; q < 4; ++q) {
          int r = rb4 + q;
          pv[p][q] = (r < CC) ? xb[r * LL + n1 + lane] : 0.f;
        }
      }
    }

    const uint32* XC = (nc & 1) ? xbf1 : xbf0;
    f32x4 acc2[2][4];
    #pragma unroll
    for (int i = 0; i < 2; ++i)
      #pragma unroll
      for (int j = 0; j < 4; ++j) acc2[i][j] = fz;

    __builtin_amdgcn_s_setprio(1);
    #pragma unroll
    for (int ks = 0; ks < 7; ++ks) {   // K = 224 (P cols 200..223 zero)
      #pragma unroll
      for (int ct = 0; ct < 4; ++ct) {
        bf16x8 b = *(const bf16x8*)&XC[(ct * 16 + lm) * TSTR + ks * 16 + lg * 4];
        acc2[0][ct] = __builtin_amdgcn_mfma_f32_16x16x32_bf16(pa[0][ks], b, acc2[0][ct], 0, 0, 0);
        if (two)
          acc2[1][ct] = __builtin_amdgcn_mfma_f32_16x16x32_bf16(pa[1][ks], b, acc2[1][ct], 0, 0, 0);
      }
    }
    __builtin_amdgcn_s_setprio(0);

    if (nc + 1 < 16) {                 // write staged regs -> other buffer
      uint32* XN = (nc & 1) ? xbf0 : xbf1;
      #pragma unroll
      for (int p = 0; p < 7; ++p) {
        int kpp = p * 8 + w;
        uint2 wv;
        wv.x = bfb(pv[p][0]) | (bfb(pv[p][1]) << 16);
        wv.y = bfb(pv[p][2]) | (bfb(pv[p][3]) << 16);
        *(uint2*)&XN[lane * TSTR + 2 * kpp] = wv;
      }
    }

    #pragma unroll
    for (int rbi = 0; rbi < 2; ++rbi) {
      if (rbi == 0 || two) {
        int rb = rbi ? rb1 : rb0;
        #pragma unroll
        for (int ct = 0; ct < 4; ++ct) {
          #pragma unroll
          for (int r = 0; r < 4; ++r) {
            int grow = rb * 16 + lg * 4 + r;
            if (grow < CC) ob[grow * LL + n0 + ct * 16 + lm] = acc2[rbi][ct][r];
          }
        }
      }
    }
  }
}

extern "C" void kernel_launch(void* const* d_in, const int* in_sizes, int n_in,
                              void* d_out, int out_size, void* d_ws, size_t ws_size,
                              hipStream_t stream) {
  const float* x = (const float*)d_in[0];
  float* out = (float*)d_out;
  const int B = in_sizes[0] / (CC * LL);   // 256
  spe_attn_kernel<<<dim3(B), dim3(512), 0, stream>>>(x, out);
}